// Round 1
// baseline (1136.308 us; speedup 1.0000x reference)
//
#include <hip/hip_runtime.h>
#include <cstdint>
#include <cstddef>

#define NEG_INF_F (-1e9f)
static constexpr int Bb = 32;
static constexpr int Rr = 4096;
static constexpr int Dd = 1024;

typedef __attribute__((ext_vector_type(8))) short short8;
typedef __attribute__((ext_vector_type(4))) float floatx4;

__device__ __forceinline__ unsigned short f2bf(float f) {
  // round-to-nearest-even fp32 -> bf16 (inputs are finite normals)
  unsigned int u = __float_as_uint(f);
  u += 0x7fffu + ((u >> 16) & 1u);
  return (unsigned short)(u >> 16);
}

// ---------------------------------------------------------------------------
// U -> bf16, swizzled to MFMA B-fragment order:
// Usw[((ks*64 + nt)*64 + lane)*8 + j] = bf16(U[k][n])
//   k = ks*32 + (lane>>4)*8 + j ; n = nt*16 + (lane&15)
// ---------------------------------------------------------------------------
__global__ void k_uswz(const float* __restrict__ U, unsigned short* __restrict__ Usw) {
  int o = blockIdx.x * 256 + threadIdx.x;           // 0 .. 1M-1
  int j = o & 7;
  int l = (o >> 3) & 63;
  int nt = (o >> 9) & 63;
  int ks = o >> 15;
  int k = ks * 32 + (l >> 4) * 8 + j;
  int n = nt * 16 + (l & 15);
  Usw[o] = f2bf(U[(size_t)k * Dd + n]);
}

// ---------------------------------------------------------------------------
// pv[b][e] = sum_d vector[b][d] * W[d][e]   (fp32, exact-ish)
// grid (D/64, B), block 64 (one wave)
// ---------------------------------------------------------------------------
__global__ void k_pv(const float* __restrict__ vec, const float* __restrict__ W,
                     float* __restrict__ pv) {
  int e = blockIdx.x * 64 + threadIdx.x;
  int b = blockIdx.y;
  const float* vb = vec + (size_t)b * Dd;
  float acc = 0.f;
#pragma unroll 8
  for (int d = 0; d < Dd; ++d) {
    acc = fmaf(vb[d], W[(size_t)d * Dd + e], acc);
  }
  pv[(size_t)b * Dd + e] = acc;
}

// ---------------------------------------------------------------------------
// Main fused kernel: per block: b fixed, 64 rows (r0..r0+63), full N=1024, K=1024
//   scores[b][r] = sum_n tanh(pm[r][n] + pv[b][n]) * v[n]
// 512 threads = 8 waves; wave w covers n in [w*128, w*128+128), all 64 rows.
// A (matrix rows) staged fp32->bf16 into LDS in fragment order, K-chunks of 256.
// B read directly from pre-swizzled Usw (L2-resident, coalesced 1KB/wave loads).
// ---------------------------------------------------------------------------
__global__ __launch_bounds__(512, 2)
void k_main(const float* __restrict__ matrix, const unsigned short* __restrict__ Usw,
            const float* __restrict__ pv, const float* __restrict__ vvec,
            float* __restrict__ scores) {
  __shared__ unsigned short As[16384];  // 8 ksteps * 4 mt * 64 lanes * 8 bf16 = 32 KB
  __shared__ float red[512];            // 8 waves * 64 rows

  const int t = threadIdx.x;
  const int w = t >> 6;
  const int l = t & 63;
  const int b = blockIdx.y;
  const int r0 = blockIdx.x * 64;
  const float* Ab = matrix + ((size_t)b * Rr + r0) * Dd;

  floatx4 acc[4][8];
#pragma unroll
  for (int mt = 0; mt < 4; ++mt)
#pragma unroll
    for (int nt = 0; nt < 8; ++nt) {
      floatx4 z = {0.f, 0.f, 0.f, 0.f};
      acc[mt][nt] = z;
    }

  const short8* Bs8 = (const short8*)Usw;
  const short8* Aw = ((const short8*)As) + l;

  for (int c = 0; c < 4; ++c) {  // K chunks of 256
    __syncthreads();
    // ---- stage A chunk: 64 rows x 256 k, fp32 -> bf16, fragment-order LDS ----
#pragma unroll
    for (int i = 0; i < 8; ++i) {
      int idx = i * 512 + t;       // 0..4095 : 64 rows * 64 float4
      int m = idx >> 6;
      int k4 = idx & 63;
      const float4* src = reinterpret_cast<const float4*>(Ab + (size_t)m * Dd + c * 256);
      float4 f = src[k4];
      int k0 = k4 * 4;
      int ks = k0 >> 5;
      int kin = k0 & 31;
      int quad = kin >> 3;
      int j0 = kin & 7;            // 0 or 4
      int mt = m >> 4;
      int m16 = m & 15;
      int base = (((ks * 4 + mt) * 64) + quad * 16 + m16) * 8 + j0;
      ushort4 pk;
      pk.x = f2bf(f.x); pk.y = f2bf(f.y); pk.z = f2bf(f.z); pk.w = f2bf(f.w);
      *reinterpret_cast<ushort4*>(&As[base]) = pk;
    }
    __syncthreads();
    // ---- compute 8 k-steps ----
#pragma unroll
    for (int ks = 0; ks < 8; ++ks) {
      const int ksg = c * 8 + ks;
      short8 a0 = Aw[(ks * 4 + 0) * 64];
      short8 a1 = Aw[(ks * 4 + 1) * 64];
      short8 a2 = Aw[(ks * 4 + 2) * 64];
      short8 a3 = Aw[(ks * 4 + 3) * 64];
      const short8* Bw = Bs8 + ((size_t)ksg * 64 + (size_t)w * 8) * 64 + l;
#pragma unroll
      for (int nt = 0; nt < 8; ++nt) {
        short8 bf = Bw[nt * 64];
        acc[0][nt] = __builtin_amdgcn_mfma_f32_16x16x32_bf16(a0, bf, acc[0][nt], 0, 0, 0);
        acc[1][nt] = __builtin_amdgcn_mfma_f32_16x16x32_bf16(a1, bf, acc[1][nt], 0, 0, 0);
        acc[2][nt] = __builtin_amdgcn_mfma_f32_16x16x32_bf16(a2, bf, acc[2][nt], 0, 0, 0);
        acc[3][nt] = __builtin_amdgcn_mfma_f32_16x16x32_bf16(a3, bf, acc[3][nt], 0, 0, 0);
      }
    }
  }

  // ---- fused epilogue: tanh(pm + pv) * v, reduce over n ----
  float part[4][4];
#pragma unroll
  for (int mt = 0; mt < 4; ++mt)
#pragma unroll
    for (int r = 0; r < 4; ++r) part[mt][r] = 0.f;

  const int n16 = l & 15;
  const int q = l >> 4;
#pragma unroll
  for (int nt = 0; nt < 8; ++nt) {
    const int col = w * 128 + nt * 16 + n16;
    const float pvv = pv[(size_t)b * Dd + col];
    const float vv = vvec[col];
#pragma unroll
    for (int mt = 0; mt < 4; ++mt) {
#pragma unroll
      for (int r = 0; r < 4; ++r) {
        float x = acc[mt][nt][r] + pvv;
        x = fminf(fmaxf(x, -10.f), 10.f);          // tanh saturates; avoid exp overflow
        float e = __expf(2.f * x);
        float th = (e - 1.f) * __builtin_amdgcn_rcpf(e + 1.f);
        part[mt][r] = fmaf(th, vv, part[mt][r]);
      }
    }
  }
  // reduce across the 16 lanes of each quad (the 16 columns of each tile)
#pragma unroll
  for (int off = 1; off < 16; off <<= 1) {
#pragma unroll
    for (int mt = 0; mt < 4; ++mt)
#pragma unroll
      for (int r = 0; r < 4; ++r)
        part[mt][r] += __shfl_xor(part[mt][r], off, 16);
  }
  if (n16 == 0) {
#pragma unroll
    for (int mt = 0; mt < 4; ++mt)
#pragma unroll
      for (int r = 0; r < 4; ++r) {
        int row = mt * 16 + q * 4 + r;
        red[w * 64 + row] = part[mt][r];
      }
  }
  __syncthreads();
  if (t < 64) {
    float s = 0.f;
#pragma unroll
    for (int ww = 0; ww < 8; ++ww) s += red[ww * 64 + t];
    scores[(size_t)b * Rr + r0 + t] = s;
  }
}

// ---------------------------------------------------------------------------
// Masked softmax over R per batch. grid B, block 256, 16 elems/thread.
// ---------------------------------------------------------------------------
__global__ void k_softmax(const float* __restrict__ scores, const int* __restrict__ mask,
                          float* __restrict__ out) {
  const int b = blockIdx.x;
  const int t = threadIdx.x;
  const float* s = scores + (size_t)b * Rr;
  const int* mk = mask + (size_t)b * Rr;
  float* o = out + (size_t)b * Rr;

  float lg[16];
  float lmax = -3.0e38f;
#pragma unroll
  for (int i = 0; i < 16; ++i) {
    int r = i * 256 + t;
    float x = (mk[r] > 0) ? s[r] : NEG_INF_F;
    lg[i] = x;
    lmax = fmaxf(lmax, x);
  }
#pragma unroll
  for (int off = 1; off < 64; off <<= 1) lmax = fmaxf(lmax, __shfl_xor(lmax, off, 64));
  __shared__ float wb1[4];
  if ((t & 63) == 0) wb1[t >> 6] = lmax;
  __syncthreads();
  lmax = fmaxf(fmaxf(wb1[0], wb1[1]), fmaxf(wb1[2], wb1[3]));

  float lsum = 0.f;
#pragma unroll
  for (int i = 0; i < 16; ++i) {
    float e = __expf(lg[i] - lmax);
    lg[i] = e;
    lsum += e;
  }
#pragma unroll
  for (int off = 1; off < 64; off <<= 1) lsum += __shfl_xor(lsum, off, 64);
  __shared__ float wb2[4];
  if ((t & 63) == 0) wb2[t >> 6] = lsum;
  __syncthreads();
  lsum = wb2[0] + wb2[1] + wb2[2] + wb2[3];
  float inv = 1.0f / lsum;
#pragma unroll
  for (int i = 0; i < 16; ++i) o[i * 256 + t] = lg[i] * inv;
}

// ---------------------------------------------------------------------------
extern "C" void kernel_launch(void* const* d_in, const int* in_sizes, int n_in,
                              void* d_out, int out_size, void* d_ws, size_t ws_size,
                              hipStream_t stream) {
  (void)in_sizes; (void)n_in; (void)out_size; (void)ws_size;
  const float* vec = (const float*)d_in[0];     // (B, D)
  const float* matrix = (const float*)d_in[1];  // (B, R, D)
  const int* mask = (const int*)d_in[2];        // (B, R)
  const float* W = (const float*)d_in[3];       // (D, D)
  const float* U = (const float*)d_in[4];       // (D, D)
  const float* v = (const float*)d_in[5];       // (D, 1)
  float* out = (float*)d_out;                   // (B, R)

  char* ws = (char*)d_ws;
  float* scores = (float*)ws;                            // 512 KB
  float* pv = (float*)(ws + 524288);                     // 128 KB
  unsigned short* Usw = (unsigned short*)(ws + 655360);  // 2 MB

  k_uswz<<<dim3((Dd * Dd) / 256), dim3(256), 0, stream>>>(U, Usw);
  k_pv<<<dim3(Dd / 64, Bb), dim3(64), 0, stream>>>(vec, W, pv);
  k_main<<<dim3(Rr / 64, Bb), dim3(512), 0, stream>>>(matrix, Usw, pv, v, scores);
  k_softmax<<<dim3(Bb), dim3(256), 0, stream>>>(scores, mask, out);
}

// Round 2
// 1031.995 us; speedup vs baseline: 1.1011x; 1.1011x over previous
//
#include <hip/hip_runtime.h>
#include <cstdint>
#include <cstddef>

#define NEG_INF_F (-1e9f)
static constexpr int Bb = 32;
static constexpr int Rr = 4096;
static constexpr int Dd = 1024;

typedef __attribute__((ext_vector_type(8))) short short8;
typedef __attribute__((ext_vector_type(4))) float floatx4;

__device__ __forceinline__ unsigned short f2bf(float f) {
  // round-to-nearest-even fp32 -> bf16 (inputs are finite normals)
  unsigned int u = __float_as_uint(f);
  u += 0x7fffu + ((u >> 16) & 1u);
  return (unsigned short)(u >> 16);
}

__device__ __forceinline__ void gload_lds16(const float* g, float* lds) {
  __builtin_amdgcn_global_load_lds(
      (const __attribute__((address_space(1))) void*)g,
      (__attribute__((address_space(3))) void*)lds,
      16, 0, 0);
}

// ---------------------------------------------------------------------------
// U -> bf16, swizzled to MFMA B-fragment order:
// Usw[((ks*64 + nt)*64 + lane)*8 + j] = bf16(U[k][n])
//   k = ks*32 + (lane>>4)*8 + j ; n = nt*16 + (lane&15)
// ---------------------------------------------------------------------------
__global__ void k_uswz(const float* __restrict__ U, unsigned short* __restrict__ Usw) {
  int o = blockIdx.x * 256 + threadIdx.x;           // 0 .. 1M-1
  int j = o & 7;
  int l = (o >> 3) & 63;
  int nt = (o >> 9) & 63;
  int ks = o >> 15;
  int k = ks * 32 + (l >> 4) * 8 + j;
  int n = nt * 16 + (l & 15);
  Usw[o] = f2bf(U[(size_t)k * Dd + n]);
}

// ---------------------------------------------------------------------------
// pv[b][e] = sum_d vector[b][d] * W[d][e]  (fp32). 4 waves split K, LDS-reduce.
// grid (D/64, B), block 256
// ---------------------------------------------------------------------------
__global__ void k_pv(const float* __restrict__ vec, const float* __restrict__ W,
                     float* __restrict__ pv) {
  __shared__ float r4[4][64];
  const int l = threadIdx.x & 63;
  const int kp = threadIdx.x >> 6;
  const int e = blockIdx.x * 64 + l;
  const int b = blockIdx.y;
  const float* vb = vec + (size_t)b * Dd;
  float acc = 0.f;
  const int d0 = kp * 256;
#pragma unroll 8
  for (int d = d0; d < d0 + 256; ++d)
    acc = fmaf(vb[d], W[(size_t)d * Dd + e], acc);
  r4[kp][l] = acc;
  __syncthreads();
  if (kp == 0)
    pv[(size_t)b * Dd + e] = (r4[0][l] + r4[1][l]) + (r4[2][l] + r4[3][l]);
}

// ---------------------------------------------------------------------------
// Main fused kernel: per block: b fixed, 64 rows, full N=1024, K chunked by 64.
//   scores[b][r] = sum_n tanh(pm[r][n] + pv[b][n]) * v[n]
// 512 threads = 8 waves; wave w covers n in [w*128, w*128+128), all 64 rows.
// A staged fp32 via async global_load_lds into fragment-order LDS (the global
// side is a per-lane gather implementing the swizzle; LDS side is lane-
// contiguous -> conflict-free). Double-buffered: prefetch chunk c+1 before
// computing chunk c; the single __syncthreads per chunk drains it after a
// full compute phase. fp32->bf16 RNE conversion happens on the LDS->reg path.
// B read directly from pre-swizzled Usw (L2-resident, 1KB/wave loads).
// ---------------------------------------------------------------------------
__global__ __launch_bounds__(512, 2)
void k_main(const float* __restrict__ matrix, const unsigned short* __restrict__ Usw,
            const float* __restrict__ pv, const float* __restrict__ vvec,
            float* __restrict__ scores) {
  __shared__ float As[2][4096];   // 2 x 16KB: 16 regions of 256 fp32 per buffer
  __shared__ float red[512];

  const int t = threadIdx.x;
  const int w = t >> 6;
  const int l = t & 63;
  const int b = blockIdx.y;
  const int r0 = blockIdx.x * 64;
  const float* Ab = matrix + ((size_t)b * Rr + r0) * Dd;

  // wave w stages the (ks2 = w>>2, mt = w&3) fragment regions of each chunk.
  // lane l gathers A[row = mt*16 + (l&15)][k = ks2*32 + (l>>4)*8 + h*4 ...]
  const int prow = (w & 3) * 16 + (l & 15);
  const int pk = ((w >> 2) << 5) + ((l >> 4) << 3);
  const float* gA = Ab + (size_t)prow * Dd + pk;

  floatx4 acc[4][8];
#pragma unroll
  for (int mt = 0; mt < 4; ++mt)
#pragma unroll
    for (int nt = 0; nt < 8; ++nt) {
      floatx4 z = {0.f, 0.f, 0.f, 0.f};
      acc[mt][nt] = z;
    }

  const short8* Bs8 = (const short8*)Usw;

  // prefetch chunk 0 into buffer 0
  {
    float* lb = &As[0][(w * 2) << 8];
    gload_lds16(gA, lb);
    gload_lds16(gA + 4, lb + 256);
  }

  for (int c = 0; c < 16; ++c) {
    const int buf = c & 1;
    __syncthreads();  // compiler-inserted vmcnt(0) drains chunk-c prefetch
    if (c + 1 < 16) {
      float* lb = &As[buf ^ 1][(w * 2) << 8];
      const float* g = gA + (c + 1) * 64;
      gload_lds16(g, lb);       // overlaps with the compute below
      gload_lds16(g + 4, lb + 256);
    }
#pragma unroll
    for (int ks2 = 0; ks2 < 2; ++ks2) {
      const int ksg = c * 2 + ks2;
      short8 af[4];
#pragma unroll
      for (int mt = 0; mt < 4; ++mt) {
        const float* p0 = &As[buf][(((ks2 * 4 + mt) << 1) << 8) + (l << 2)];
        float4 lo = *(const float4*)p0;
        float4 hi = *(const float4*)(p0 + 256);
        af[mt][0] = (short)f2bf(lo.x); af[mt][1] = (short)f2bf(lo.y);
        af[mt][2] = (short)f2bf(lo.z); af[mt][3] = (short)f2bf(lo.w);
        af[mt][4] = (short)f2bf(hi.x); af[mt][5] = (short)f2bf(hi.y);
        af[mt][6] = (short)f2bf(hi.z); af[mt][7] = (short)f2bf(hi.w);
      }
      const short8* Bw = Bs8 + ((size_t)ksg * 64 + (size_t)w * 8) * 64 + l;
#pragma unroll
      for (int nt = 0; nt < 8; ++nt) {
        short8 bf = Bw[nt * 64];
        acc[0][nt] = __builtin_amdgcn_mfma_f32_16x16x32_bf16(af[0], bf, acc[0][nt], 0, 0, 0);
        acc[1][nt] = __builtin_amdgcn_mfma_f32_16x16x32_bf16(af[1], bf, acc[1][nt], 0, 0, 0);
        acc[2][nt] = __builtin_amdgcn_mfma_f32_16x16x32_bf16(af[2], bf, acc[2][nt], 0, 0, 0);
        acc[3][nt] = __builtin_amdgcn_mfma_f32_16x16x32_bf16(af[3], bf, acc[3][nt], 0, 0, 0);
      }
    }
  }

  // ---- fused epilogue: tanh(pm + pv) * v, reduce over n ----
  float part[4][4];
#pragma unroll
  for (int mt = 0; mt < 4; ++mt)
#pragma unroll
    for (int r = 0; r < 4; ++r) part[mt][r] = 0.f;

  const int n16 = l & 15;
  const int q = l >> 4;
#pragma unroll
  for (int nt = 0; nt < 8; ++nt) {
    const int col = w * 128 + nt * 16 + n16;
    const float pvv = pv[(size_t)b * Dd + col];
    const float vv = vvec[col];
#pragma unroll
    for (int mt = 0; mt < 4; ++mt) {
#pragma unroll
      for (int r = 0; r < 4; ++r) {
        float x = acc[mt][nt][r] + pvv;
        x = fminf(fmaxf(x, -10.f), 10.f);          // tanh saturates; avoid exp overflow
        float e = __expf(2.f * x);
        float th = (e - 1.f) * __builtin_amdgcn_rcpf(e + 1.f);
        part[mt][r] = fmaf(th, vv, part[mt][r]);
      }
    }
  }
  // reduce across the 16 lanes of each quad (the 16 columns of each tile)
#pragma unroll
  for (int off = 1; off < 16; off <<= 1) {
#pragma unroll
    for (int mt = 0; mt < 4; ++mt)
#pragma unroll
      for (int r = 0; r < 4; ++r)
        part[mt][r] += __shfl_xor(part[mt][r], off, 16);
  }
  if (n16 == 0) {
#pragma unroll
    for (int mt = 0; mt < 4; ++mt)
#pragma unroll
      for (int r = 0; r < 4; ++r) {
        int row = mt * 16 + q * 4 + r;
        red[w * 64 + row] = part[mt][r];
      }
  }
  __syncthreads();
  if (t < 64) {
    float s = 0.f;
#pragma unroll
    for (int ww = 0; ww < 8; ++ww) s += red[ww * 64 + t];
    scores[(size_t)b * Rr + r0 + t] = s;
  }
}

// ---------------------------------------------------------------------------
// Masked softmax over R per batch. grid B, block 256, 16 elems/thread.
// ---------------------------------------------------------------------------
__global__ void k_softmax(const float* __restrict__ scores, const int* __restrict__ mask,
                          float* __restrict__ out) {
  const int b = blockIdx.x;
  const int t = threadIdx.x;
  const float* s = scores + (size_t)b * Rr;
  const int* mk = mask + (size_t)b * Rr;
  float* o = out + (size_t)b * Rr;

  float lg[16];
  float lmax = -3.0e38f;
#pragma unroll
  for (int i = 0; i < 16; ++i) {
    int r = i * 256 + t;
    float x = (mk[r] > 0) ? s[r] : NEG_INF_F;
    lg[i] = x;
    lmax = fmaxf(lmax, x);
  }
#pragma unroll
  for (int off = 1; off < 64; off <<= 1) lmax = fmaxf(lmax, __shfl_xor(lmax, off, 64));
  __shared__ float wb1[4];
  if ((t & 63) == 0) wb1[t >> 6] = lmax;
  __syncthreads();
  lmax = fmaxf(fmaxf(wb1[0], wb1[1]), fmaxf(wb1[2], wb1[3]));

  float lsum = 0.f;
#pragma unroll
  for (int i = 0; i < 16; ++i) {
    float e = __expf(lg[i] - lmax);
    lg[i] = e;
    lsum += e;
  }
#pragma unroll
  for (int off = 1; off < 64; off <<= 1) lsum += __shfl_xor(lsum, off, 64);
  __shared__ float wb2[4];
  if ((t & 63) == 0) wb2[t >> 6] = lsum;
  __syncthreads();
  lsum = wb2[0] + wb2[1] + wb2[2] + wb2[3];
  float inv = 1.0f / lsum;
#pragma unroll
  for (int i = 0; i < 16; ++i) o[i * 256 + t] = lg[i] * inv;
}

// ---------------------------------------------------------------------------
extern "C" void kernel_launch(void* const* d_in, const int* in_sizes, int n_in,
                              void* d_out, int out_size, void* d_ws, size_t ws_size,
                              hipStream_t stream) {
  (void)in_sizes; (void)n_in; (void)out_size; (void)ws_size;
  const float* vec = (const float*)d_in[0];     // (B, D)
  const float* matrix = (const float*)d_in[1];  // (B, R, D)
  const int* mask = (const int*)d_in[2];        // (B, R)
  const float* W = (const float*)d_in[3];       // (D, D)
  const float* U = (const float*)d_in[4];       // (D, D)
  const float* v = (const float*)d_in[5];       // (D, 1)
  float* out = (float*)d_out;                   // (B, R)

  char* ws = (char*)d_ws;
  float* scores = (float*)ws;                            // 512 KB
  float* pv = (float*)(ws + 524288);                     // 128 KB
  unsigned short* Usw = (unsigned short*)(ws + 655360);  // 2 MB

  k_uswz<<<dim3((Dd * Dd) / 256), dim3(256), 0, stream>>>(U, Usw);
  k_pv<<<dim3(Dd / 64, Bb), dim3(256), 0, stream>>>(vec, W, pv);
  k_main<<<dim3(Rr / 64, Bb), dim3(512), 0, stream>>>(matrix, Usw, pv, v, scores);
  k_softmax<<<dim3(Bb), dim3(256), 0, stream>>>(scores, mask, out);
}